// Round 1
// baseline (681.257 us; speedup 1.0000x reference)
//
#include <hip/hip_runtime.h>

#define BB 2
#define TT 2048
#define DD 1024
#define NN 16
#define LL 16
#define CC (TT / LL) /* 128 chunks */

// ---------------------------------------------------------------------------
// K1: per-(b,d,n) sequential carry over all chunks. Reads delta (all t) and
// b_mat/u at chunk-first timesteps only. Stores h_in at segment boundaries.
// ---------------------------------------------------------------------------
__global__ __launch_bounds__(256) void k1_carry(
    const float* __restrict__ delta,
    const float* __restrict__ u,
    const float* __restrict__ bmat,
    const float* __restrict__ A_log,
    float* __restrict__ hin,
    int S, int CPS)
{
    int g = blockIdx.x * 256 + threadIdx.x;   // B*D*N = 32768 threads
    int n = g & (NN - 1);
    int d = (g >> 4) & (DD - 1);
    int b = g >> 14;

    float A_n  = -__expf(A_log[n]);
    float rinv = 1.0f / (A_n + 1e-12f);

    float h = 0.0f;
    for (int c = 0; c < CC; ++c) {
        if ((c & (CPS - 1)) == 0) {
            int seg = c / CPS;
            hin[((b * S + seg) * DD + d) * NN + n] = h;
        }
        int t0 = c * LL;
        int base = (b * TT + t0) * DD + d;

        float dl[LL];
        #pragma unroll
        for (int t = 0; t < LL; ++t) dl[t] = delta[base + t * DD];
        float bm0 = bmat[base * NN + n];
        float uu0 = u[base];

        float p = 1.0f;
        float Q = 0.0f;
        #pragma unroll
        for (int t = 0; t < LL; ++t) {
            float dA = fminf(fmaxf(dl[t] * A_n, -10.0f), 10.0f);
            float eA = __expf(dA);
            if (t == 0) {
                float frac = (fabsf(dA) < 1e-4f) ? dl[t] : (eA - 1.0f) * rinv;
                // Bu[0]*fw[0] with fw[0] = eA[0]  (L > 1)
                Q = frac * (bm0 * uu0) * eA;
            }
            p *= eA;                 // left-to-right cumprod, matches reference
        }
        h = h * p + Q;               // h_new[:, -1]
    }
}

// ---------------------------------------------------------------------------
// K2: per-(b,seg,d,n) full computation over the segment's chunks.
// Block = 256 threads = 16 d-values x 16 n-values. Coalesced 256B/wave loads
// of b_mat/c_mat; n-reduction via shfl_xor butterfly within 16-lane groups.
// ---------------------------------------------------------------------------
__global__ __launch_bounds__(256) void k2_main(
    const float* __restrict__ delta,
    const float* __restrict__ u,
    const float* __restrict__ bmat,
    const float* __restrict__ cmat,
    const float* __restrict__ A_log,
    const float* __restrict__ hin,
    float* __restrict__ out,
    int S, int CPS)
{
    const int dblks = DD / 16;
    int blocks_per_b = S * dblks;
    int b   = blockIdx.x / blocks_per_b;
    int r   = blockIdx.x - b * blocks_per_b;
    int seg = r / dblks;
    int dblk = r - seg * dblks;

    int n = threadIdx.x & 15;
    int d = dblk * 16 + (threadIdx.x >> 4);

    float A_n  = -__expf(A_log[n]);
    float rinv = 1.0f / (A_n + 1e-12f);

    float h = hin[((b * S + seg) * DD + d) * NN + n];
    int t0seg = seg * (TT / S);

    for (int c = 0; c < CPS; ++c) {
        int t0 = t0seg + c * LL;
        int base = (b * TT + t0) * DD + d;

        // Stage one chunk of inputs into registers (16 independent loads each).
        float dl[LL], bu[LL], cm[LL];
        #pragma unroll
        for (int t = 0; t < LL; ++t) {
            int bt = base + t * DD;
            dl[t] = delta[bt];
            float uu = u[bt];
            float bm = bmat[bt * NN + n];
            cm[t] = cmat[bt * NN + n];
            bu[t] = bm * uu;          // b * u  (reference association)
        }

        // cumprod of eA and left-to-right prefix sum of g = Bu*fw.
        float cp[LL], pref[LL];
        float prun = 1.0f, srun = 0.0f;
        #pragma unroll
        for (int t = 0; t < LL; ++t) {
            float dA = fminf(fmaxf(dl[t] * A_n, -10.0f), 10.0f);
            float eA = __expf(dA);
            float frac = (fabsf(dA) < 1e-4f) ? dl[t] : (eA - 1.0f) * rinv;
            float Bu = frac * bu[t];
            float gg = Bu * ((t < LL - 1) ? eA : 1.0f);   // fw[t]
            prun *= eA;
            cp[t] = prun;
            srun += gg;
            pref[t] = srun;
        }

        // h_new[t] = h*cp[t] + pref[L-1-t]  (flip of cumsum, per reference);
        // y[t] = sum_n h_new[t]*c[t]  via 16-lane butterfly.
        float yv = 0.0f;
        #pragma unroll
        for (int t = 0; t < LL; ++t) {
            float hn = h * cp[t] + pref[LL - 1 - t];
            float v  = hn * cm[t];
            v += __shfl_xor(v, 1);
            v += __shfl_xor(v, 2);
            v += __shfl_xor(v, 4);
            v += __shfl_xor(v, 8);
            if (n == t) yv = v;      // lane n keeps y for timestep t0+n
        }
        h = h * cp[LL - 1] + pref[0];   // carry = h_new[L-1]

        out[base + n * DD] = yv;        // out[b, t0+n, d]
    }
}

// ---------------------------------------------------------------------------
extern "C" void kernel_launch(void* const* d_in, const int* in_sizes, int n_in,
                              void* d_out, int out_size, void* d_ws, size_t ws_size,
                              hipStream_t stream) {
    (void)in_sizes; (void)n_in; (void)out_size;

    const float* u     = (const float*)d_in[0];
    const float* delta = (const float*)d_in[1];
    const float* bmat  = (const float*)d_in[2];
    const float* cmat  = (const float*)d_in[3];
    const float* A_log = (const float*)d_in[4];
    float* out = (float*)d_out;
    float* hin = (float*)d_ws;

    // Segments: more = more parallelism in K2; h_in table must fit in ws.
    int S = 32;
    while ((size_t)BB * (size_t)S * DD * NN * sizeof(float) > ws_size && S > 1)
        S >>= 1;
    int CPS = CC / S;   // chunks per segment

    k1_carry<<<BB * DD * NN / 256, 256, 0, stream>>>(delta, u, bmat, A_log, hin, S, CPS);
    k2_main<<<BB * S * (DD / 16), 256, 0, stream>>>(delta, u, bmat, cmat, A_log, hin, out, S, CPS);
}

// Round 2
// 597.559 us; speedup vs baseline: 1.1401x; 1.1401x over previous
//
#include <hip/hip_runtime.h>

#define BB 2
#define TT 2048
#define DD 1024
#define NN 16
#define LL 16
#define CC (TT / LL) /* 128 chunks */

// ---------------------------------------------------------------------------
// K1a: per-(b,seg,d,n) segment affine transform (P,Q) over CPS chunks.
// h_out = h_in * P + Q. 1M threads -> latency fully hidden.
// g = ((b*S+seg)*DD+d)*NN+n so P/Q writes are perfectly coalesced and the
// 16 n-lanes broadcast-share each delta/u address.
// ---------------------------------------------------------------------------
__global__ __launch_bounds__(256) void k1a_segxform(
    const float* __restrict__ delta,
    const float* __restrict__ u,
    const float* __restrict__ bmat,
    const float* __restrict__ A_log,
    float* __restrict__ Pseg,
    float* __restrict__ Qseg,
    int S, int CPS)
{
    int g = blockIdx.x * 256 + threadIdx.x;     // B*S*D*N threads
    int n   = g & (NN - 1);
    int d   = (g >> 4) & (DD - 1);
    int seg = (g >> 14) & (S - 1);
    int b   = g >> (14 + 5);                    // S=32 fixed by launch

    float A_n  = -__expf(A_log[n]);
    float rinv = 1.0f / (A_n + 1e-12f);

    float P = 1.0f, Q = 0.0f;
    int c0 = seg * CPS;
    for (int c = c0; c < c0 + CPS; ++c) {
        int t0 = c * LL;
        int base = (b * TT + t0) * DD + d;

        float dl[LL];
        #pragma unroll
        for (int t = 0; t < LL; ++t) dl[t] = delta[base + t * DD];
        float bm0 = bmat[base * NN + n];
        float uu0 = u[base];

        float p = 1.0f;
        float q = 0.0f;
        #pragma unroll
        for (int t = 0; t < LL; ++t) {
            float dA = fminf(fmaxf(dl[t] * A_n, -10.0f), 10.0f);
            float eA = __expf(dA);
            if (t == 0) {
                float frac = (fabsf(dA) < 1e-4f) ? dl[t] : (eA - 1.0f) * rinv;
                q = frac * (bm0 * uu0) * eA;    // Bu[0]*fw[0], fw[0]=eA[0]
            }
            p *= eA;
        }
        // compose chunk transform: h -> h*p + q
        P = P * p;
        Q = Q * p + q;
    }
    Pseg[g] = P;
    Qseg[g] = Q;
}

// ---------------------------------------------------------------------------
// K1b: tiny sequential scan over S segments per (b,d,n). Writes h_in table.
// ---------------------------------------------------------------------------
__global__ __launch_bounds__(256) void k1b_scan(
    const float* __restrict__ Pseg,
    const float* __restrict__ Qseg,
    float* __restrict__ hin,
    int S)
{
    int g = blockIdx.x * 256 + threadIdx.x;     // B*D*N threads
    int dn = g & (DD * NN - 1);                 // (d,n) packed, contiguous
    int b  = g >> 14;

    float h = 0.0f;
    for (int s = 0; s < S; ++s) {
        int idx = (b * S + s) * (DD * NN) + dn; // coalesced across lanes
        hin[idx] = h;
        h = h * Pseg[idx] + Qseg[idx];
    }
}

// ---------------------------------------------------------------------------
// K2: unchanged from round 1 (per-(b,seg,d,n), 16-lane butterfly reduction).
// ---------------------------------------------------------------------------
__global__ __launch_bounds__(256) void k2_main(
    const float* __restrict__ delta,
    const float* __restrict__ u,
    const float* __restrict__ bmat,
    const float* __restrict__ cmat,
    const float* __restrict__ A_log,
    const float* __restrict__ hin,
    float* __restrict__ out,
    int S, int CPS)
{
    const int dblks = DD / 16;
    int blocks_per_b = S * dblks;
    int b   = blockIdx.x / blocks_per_b;
    int r   = blockIdx.x - b * blocks_per_b;
    int seg = r / dblks;
    int dblk = r - seg * dblks;

    int n = threadIdx.x & 15;
    int d = dblk * 16 + (threadIdx.x >> 4);

    float A_n  = -__expf(A_log[n]);
    float rinv = 1.0f / (A_n + 1e-12f);

    float h = hin[((b * S + seg) * DD + d) * NN + n];
    int t0seg = seg * (TT / S);

    for (int c = 0; c < CPS; ++c) {
        int t0 = t0seg + c * LL;
        int base = (b * TT + t0) * DD + d;

        float dl[LL], bu[LL], cm[LL];
        #pragma unroll
        for (int t = 0; t < LL; ++t) {
            int bt = base + t * DD;
            dl[t] = delta[bt];
            float uu = u[bt];
            float bm = bmat[bt * NN + n];
            cm[t] = cmat[bt * NN + n];
            bu[t] = bm * uu;
        }

        float cp[LL], pref[LL];
        float prun = 1.0f, srun = 0.0f;
        #pragma unroll
        for (int t = 0; t < LL; ++t) {
            float dA = fminf(fmaxf(dl[t] * A_n, -10.0f), 10.0f);
            float eA = __expf(dA);
            float frac = (fabsf(dA) < 1e-4f) ? dl[t] : (eA - 1.0f) * rinv;
            float Bu = frac * bu[t];
            float gg = Bu * ((t < LL - 1) ? eA : 1.0f);
            prun *= eA;
            cp[t] = prun;
            srun += gg;
            pref[t] = srun;
        }

        float yv = 0.0f;
        #pragma unroll
        for (int t = 0; t < LL; ++t) {
            float hn = h * cp[t] + pref[LL - 1 - t];
            float v  = hn * cm[t];
            v += __shfl_xor(v, 1);
            v += __shfl_xor(v, 2);
            v += __shfl_xor(v, 4);
            v += __shfl_xor(v, 8);
            if (n == t) yv = v;
        }
        h = h * cp[LL - 1] + pref[0];

        out[base + n * DD] = yv;
    }
}

// ---------------------------------------------------------------------------
extern "C" void kernel_launch(void* const* d_in, const int* in_sizes, int n_in,
                              void* d_out, int out_size, void* d_ws, size_t ws_size,
                              hipStream_t stream) {
    (void)in_sizes; (void)n_in; (void)out_size;

    const float* u     = (const float*)d_in[0];
    const float* delta = (const float*)d_in[1];
    const float* bmat  = (const float*)d_in[2];
    const float* cmat  = (const float*)d_in[3];
    const float* A_log = (const float*)d_in[4];
    float* out = (float*)d_out;

    const int S = 32;                 // segments (k1a bit math assumes 32)
    const int CPS = CC / S;           // chunks per segment = 4

    size_t tbl = (size_t)BB * S * DD * NN;     // 1M floats = 4 MB each
    float* Pseg = (float*)d_ws;
    float* Qseg = Pseg + tbl;
    float* hin  = Qseg + tbl;
    (void)ws_size;  // requires 12 MB of workspace

    k1a_segxform<<<(BB * S * DD * NN) / 256, 256, 0, stream>>>(
        delta, u, bmat, A_log, Pseg, Qseg, S, CPS);
    k1b_scan<<<(BB * DD * NN) / 256, 256, 0, stream>>>(Pseg, Qseg, hin, S);
    k2_main<<<BB * S * (DD / 16), 256, 0, stream>>>(
        delta, u, bmat, cmat, A_log, hin, out, S, CPS);
}